// Round 9
// baseline (371.343 us; speedup 1.0000x reference)
//
#include <hip/hip_runtime.h>
#include <math.h>

#define EPSF 1e-8f

typedef float nvec4 __attribute__((ext_vector_type(4)));

__device__ __forceinline__ float wave_sum(float v) {
#pragma unroll
    for (int m = 32; m; m >>= 1) v += __shfl_xor(v, m, 64);
    return v;
}

// ---------------- K1: template weights + common_template ----------------
// grid 64, block 256 (thread = channel). Tiny kernel.
__global__ void k_template(const float* __restrict__ tpl,
                           float* __restrict__ out1,   // (64,257,4,4)
                           float* __restrict__ out3) { // (64,1,4,4)
    int b = blockIdx.x;
    int c = threadIdx.x;
    const float* p = tpl + ((size_t)(b * 256 + c)) * 16;
    float4 r0 = ((const float4*)p)[0];
    float4 r1 = ((const float4*)p)[1];
    float4 r2 = ((const float4*)p)[2];
    float4 r3 = ((const float4*)p)[3];
    float t[16] = {r0.x, r0.y, r0.z, r0.w, r1.x, r1.y, r1.z, r1.w,
                   r2.x, r2.y, r2.z, r2.w, r3.x, r3.y, r3.z, r3.w};
    float s = 0.f;
#pragma unroll
    for (int i = 0; i < 16; i++) s += t[i];
    float m = s * (1.f / 16.f);

    float vals[33];
#pragma unroll
    for (int i = 0; i < 16; i++) { vals[i] = m * t[i]; vals[16 + i] = t[i] * t[i]; }
    vals[32] = m * m;

    __shared__ float red[4][33];
    int wave = threadIdx.x >> 6, lane = threadIdx.x & 63;
#pragma unroll
    for (int i = 0; i < 33; i++) {
        float r = wave_sum(vals[i]);
        if (lane == 0) red[wave][i] = r;
    }
    __syncthreads();

    __shared__ float wn[16];
    if (threadIdx.x < 16) {
        int sI = threadIdx.x;
        float dot = red[0][sI] + red[1][sI] + red[2][sI] + red[3][sI];
        float nb2 = red[0][16 + sI] + red[1][16 + sI] + red[2][16 + sI] + red[3][16 + sI];
        float na2 = red[0][32] + red[1][32] + red[2][32] + red[3][32];
        float w = dot / (fmaxf(sqrtf(na2), EPSF) * fmaxf(sqrtf(nb2), EPSF));
        float mx = w;
#pragma unroll
        for (int msk = 8; msk; msk >>= 1) mx = fmaxf(mx, __shfl_xor(mx, msk, 16));
        float e = expf(w - mx);
        float sm = e;
#pragma unroll
        for (int msk = 8; msk; msk >>= 1) sm += __shfl_xor(sm, msk, 16);
        float v = e / sm;
        wn[sI] = v;
        out3[b * 16 + sI] = v;
    }
    __syncthreads();

    float* o = out1 + ((size_t)(b * 257 + c)) * 16;
    ((float4*)o)[0] = r0; ((float4*)o)[1] = r1;
    ((float4*)o)[2] = r2; ((float4*)o)[3] = r3;
    if (threadIdx.x < 16)
        out1[((size_t)(b * 257 + 256)) * 16 + threadIdx.x] = wn[threadIdx.x];
}

// ---------------- K0: transpose cand (b,c,yx) -> candT (b,yx,c) ----------------
// grid (13, 8, 64), block (32, 8). Coalesced both ways via 32x33 LDS tile.
__global__ void k_transpose(const float* __restrict__ in,
                            float* __restrict__ outT) {
    __shared__ float tile[32][33];
    int b = blockIdx.z;
    int p0 = blockIdx.x * 32;   // position tile (0..399)
    int c0 = blockIdx.y * 32;   // channel tile  (0..255)
    int tx = threadIdx.x;       // 0..31
    int ty = threadIdx.y;       // 0..7
    const float* src = in + (size_t)b * 102400;
#pragma unroll
    for (int r = ty; r < 32; r += 8) {
        int pos = p0 + tx;
        if (pos < 400) tile[r][tx] = src[(size_t)(c0 + r) * 400 + pos];
    }
    __syncthreads();
    float* dst = outT + (size_t)b * 102400;
#pragma unroll
    for (int r = ty; r < 32; r += 8) {
        int pos = p0 + r;
        if (pos < 400) dst[(size_t)pos * 256 + c0 + tx] = tile[tx][r];
    }
}

// ---------------- K2: per-window cosine weight ----------------
// grid 64*289, block 64 (ONE wave). Lane owns 4 CONSECUTIVE channels via one
// float4 load per window cell: 16 dwordx4 loads/lane (coalesced 1KB per wave
// instr), accumulates dot/nb2/na2 across its 4 components in registers, then
// one LDS-transpose reduction (33 ds_write + 64 ds_read, rows padded to 65).
// XCD-chunked block swizzle (T1): nwg = 18496 = 8*2312 (bijective). All 289
// windows of a batch share its 410 KB candT panel; chunking keeps the 11.6x
// logical reuse (302 MB) inside one XCD's 4 MB L2 instead of bouncing to L3.
__global__ void k_cand_stats(const float* __restrict__ candT,
                             float* __restrict__ wsW) {  // [b][4624] flat (i,j,p,q)
    int bx0 = blockIdx.x;           // 0..18495, dispatch order (xcd = bx0 % 8)
    int xcd = bx0 & 7;
    int bx  = xcd * 2312 + (bx0 >> 3);   // same-XCD blocks -> contiguous work
    int b = bx / 289, pq = bx - b * 289;
    int p = pq / 17, q = pq - p * 17;
    int lane = threadIdx.x;     // 0..63; channels lane*4 .. lane*4+3
    const float4* base = (const float4*)(candT + ((size_t)(b * 400 + p * 20 + q)) * 256) + lane;

    float4 w[16];
#pragma unroll
    for (int di = 0; di < 4; di++)
#pragma unroll
        for (int dj = 0; dj < 4; dj++)
            w[di * 4 + dj] = base[(size_t)(di * 20 + dj) * 64];

    float4 s4 = make_float4(0.f, 0.f, 0.f, 0.f);
#pragma unroll
    for (int t = 0; t < 16; t++) {
        s4.x += w[t].x; s4.y += w[t].y; s4.z += w[t].z; s4.w += w[t].w;
    }
    float4 m4 = make_float4(s4.x * (1.f/16.f), s4.y * (1.f/16.f),
                            s4.z * (1.f/16.f), s4.w * (1.f/16.f));

    float accDot[16], accNb2[16];
#pragma unroll
    for (int t = 0; t < 16; t++) {
        accDot[t] = m4.x * w[t].x + m4.y * w[t].y + m4.z * w[t].z + m4.w * w[t].w;
        accNb2[t] = w[t].x * w[t].x + w[t].y * w[t].y + w[t].z * w[t].z + w[t].w * w[t].w;
    }
    float accNa2 = m4.x * m4.x + m4.y * m4.y + m4.z * m4.z + m4.w * m4.w;

    __shared__ float red[33 * 65];
    __shared__ float sums[33];
#pragma unroll
    for (int i = 0; i < 16; i++) red[i * 65 + lane] = accDot[i];
#pragma unroll
    for (int i = 0; i < 16; i++) red[(16 + i) * 65 + lane] = accNb2[i];
    red[32 * 65 + lane] = accNa2;
    __syncthreads();
    if (lane < 33) {
        const float* row = &red[lane * 65];
        float s = 0.f;
#pragma unroll
        for (int j = 0; j < 64; j++) s += row[j];
        sums[lane] = s;
    }
    __syncthreads();
    if (lane < 16) {
        float dot = sums[lane], nb2 = sums[16 + lane], na2 = sums[32];
        float w0 = dot / (fmaxf(sqrtf(na2), EPSF) * fmaxf(sqrtf(nb2), EPSF));
        // flat (i,j,p,q) order to match reshape(B,-1)
        wsW[(size_t)b * 4624 + lane * 289 + pq] = w0;
    }
}

// ---------------- K3: per-batch softmax over 4624 ----------------
// grid 64, block 512. Contiguous reads of wsW.
__global__ void k_softmax(const float* __restrict__ wsW,
                          float* __restrict__ wsSm) {
    int b = blockIdx.x;
    int tid = threadIdx.x;
    __shared__ float wv[4624];
    __shared__ float red[8];
    __shared__ float bcast;
    int wave = tid >> 6, lane = tid & 63;

    float lmax = -1e30f;
    for (int f = tid; f < 4624; f += 512) {
        float w = wsW[(size_t)b * 4624 + f];
        wv[f] = w;
        lmax = fmaxf(lmax, w);
    }
#pragma unroll
    for (int m = 32; m; m >>= 1) lmax = fmaxf(lmax, __shfl_xor(lmax, m, 64));
    if (lane == 0) red[wave] = lmax;
    __syncthreads();
    if (tid == 0) {
        float M = red[0];
        for (int i = 1; i < 8; i++) M = fmaxf(M, red[i]);
        bcast = M;
    }
    __syncthreads();
    float M = bcast;

    float lsum = 0.f;
    for (int f = tid; f < 4624; f += 512) {
        float e = expf(wv[f] - M);
        wv[f] = e;
        lsum += e;
    }
    __syncthreads();
    lsum = wave_sum(lsum);
    if (lane == 0) red[wave] = lsum;
    __syncthreads();
    if (tid == 0) {
        float S = 0.f;
        for (int i = 0; i < 8; i++) S += red[i];
        bcast = S;
    }
    __syncthreads();
    float inv = 1.f / bcast;
    for (int f = tid; f < 4624; f += 512)
        wsSm[(size_t)b * 4624 + f] = wv[f] * inv;
}

// ---------------- K4: expansion writer ----------------
// grid (257, 64), block 256. ~305 MB of nontemporal float4 stores — the HBM
// floor (~50 us at the 6.35 TB/s the harness's own fill achieves).
// Index math: f4 = i*289 + rr (i exact on float4 boundaries since 1156=4*289),
// element r = 4*rr + e in the (j,p,q) 1156-space.
__global__ void __launch_bounds__(256) k_writer(
                         const float* __restrict__ cand,
                         const float* __restrict__ wsSm,
                         float* __restrict__ out2,   // (64,257,4,4,17,17)
                         float* __restrict__ out4) { // (64,1,4,4,17,17)
    int ch = blockIdx.x;
    int b = blockIdx.y;
    int tid = threadIdx.x;
    __shared__ float lds[4624];

    if (ch < 256) {
        const float* src = cand + ((size_t)(b * 256 + ch)) * 400;
        if (tid < 256) lds[tid] = src[tid];
        if (tid < 144) lds[tid + 256] = src[tid + 256];
        __syncthreads();
        nvec4* ob = (nvec4*)(out2 + ((size_t)(b * 257 + ch)) * 4624);
#pragma unroll
        for (int it = 0; it < 5; it++) {
            int f4 = tid + it * 256;
            if (f4 < 1156) {
                int i  = f4 / 289;        // 0..3, constant within the float4
                int rr = f4 - i * 289;    // 0..288
                nvec4 vv;
#pragma unroll
                for (int e = 0; e < 4; e++) {
                    int r  = rr * 4 + e;      // 0..1155 in (j,p,q)
                    int j  = r / 289;
                    int r2 = r - j * 289;
                    int pp = r2 / 17;
                    int qq = r2 - pp * 17;
                    vv[e] = lds[(i + pp) * 20 + (j + qq)];
                }
                __builtin_nontemporal_store(vv, &ob[f4]);
            }
        }
    } else {
        const float* src = wsSm + (size_t)b * 4624;
        for (int f = tid; f < 4624; f += 256) lds[f] = src[f];
        __syncthreads();
        nvec4* ob = (nvec4*)(out2 + ((size_t)(b * 257 + 256)) * 4624);
        nvec4* o4 = (nvec4*)(out4 + (size_t)b * 4624);
#pragma unroll
        for (int it = 0; it < 5; it++) {
            int f4 = tid + it * 256;
            if (f4 < 1156) {
                int i  = f4 / 289;
                int rr = f4 - i * 289;
                nvec4 vv;
#pragma unroll
                for (int e = 0; e < 4; e++) {
                    int r  = rr * 4 + e;
                    int j  = r / 289;
                    int r2 = r - j * 289;
                    int pp = r2 / 17;
                    int qq = r2 - pp * 17;
                    // wc_norm[b,0,i,j,p,q] = sm_flat[(p*17+q)*16 + i*4 + j]
                    vv[e] = lds[(pp * 17 + qq) * 16 + i * 4 + j];
                }
                __builtin_nontemporal_store(vv, &ob[f4]);
                __builtin_nontemporal_store(vv, &o4[f4]);
            }
        }
    }
}

extern "C" void kernel_launch(void* const* d_in, const int* in_sizes, int n_in,
                              void* d_out, int out_size, void* d_ws, size_t ws_size,
                              hipStream_t stream) {
    const float* tpl  = (const float*)d_in[0];   // (64,256,4,4)
    const float* cand = (const float*)d_in[1];   // (64,256,20,20)
    float* out = (float*)d_out;
    // tuple flat-concat offsets
    float* out1 = out;                  // 263168
    float* out2 = out + 263168;         // 76067072
    float* out3 = out + 76330240;       // 1024
    float* out4 = out + 76331264;       // 295936

    float* ws = (float*)d_ws;
    float* wsW  = ws;                   // 64*4624 floats
    float* wsSm = ws + 295936;          // 64*4624 floats

    // candT (64,400,256) = 26.2 MB stashed at the head of out2's region.
    // Stream order: K0 writes it, K2 reads it, K4 later overwrites all of out2.
    float* candT = out2;

    k_template  <<<64,                      256,          0, stream>>>(tpl, out1, out3);
    k_transpose <<<dim3(13, 8, 64),         dim3(32, 8),  0, stream>>>(cand, candT);
    k_cand_stats<<<64 * 289,                64,           0, stream>>>(candT, wsW);
    k_softmax   <<<64,                      512,          0, stream>>>(wsW, wsSm);
    k_writer    <<<dim3(257, 64),           256,          0, stream>>>(cand, wsSm, out2, out4);
}

// Round 10
// 360.853 us; speedup vs baseline: 1.0291x; 1.0291x over previous
//
#include <hip/hip_runtime.h>
#include <math.h>

#define EPSF 1e-8f

typedef float nvec4 __attribute__((ext_vector_type(4)));

__device__ __forceinline__ float wave_sum(float v) {
#pragma unroll
    for (int m = 32; m; m >>= 1) v += __shfl_xor(v, m, 64);
    return v;
}

// ---------------- kA: fused prep = transpose (6656 blocks) + template (64) ----
// transpose: cand (b,c,yx) -> candT (b,yx,c), coalesced both ways via LDS tile.
// template: per-batch cosine weights + softmax + common_template write.
__global__ void __launch_bounds__(256) k_prep(
                       const float* __restrict__ cand,
                       float* __restrict__ candT,
                       const float* __restrict__ tpl,
                       float* __restrict__ out1,   // (64,257,4,4)
                       float* __restrict__ out3) { // (64,1,4,4)
    __shared__ float tile[32][33];
    __shared__ float red[4][33];
    __shared__ float wn[16];
    int bx = blockIdx.x;
    int tid = threadIdx.x;

    if (bx < 6656) {
        // ---- transpose block: bx -> (xt 0..12, yt 0..7, b 0..63)
        int xt  = bx % 13;
        int rem = bx / 13;
        int yt  = rem & 7;
        int b   = rem >> 3;
        int p0 = xt * 32;       // position tile (0..399)
        int c0 = yt * 32;       // channel tile
        int tx = tid & 31, ty = tid >> 5;   // (32,8)
        const float* src = cand + (size_t)b * 102400;
#pragma unroll
        for (int r = ty; r < 32; r += 8) {
            int pos = p0 + tx;
            if (pos < 400) tile[r][tx] = src[(size_t)(c0 + r) * 400 + pos];
        }
        __syncthreads();
        float* dst = candT + (size_t)b * 102400;
#pragma unroll
        for (int r = ty; r < 32; r += 8) {
            int pos = p0 + r;
            if (pos < 400) dst[(size_t)pos * 256 + c0 + tx] = tile[tx][r];
        }
    } else {
        // ---- template block: thread = channel
        int b = bx - 6656;
        int c = tid;
        const float* p = tpl + ((size_t)(b * 256 + c)) * 16;
        float4 r0 = ((const float4*)p)[0];
        float4 r1 = ((const float4*)p)[1];
        float4 r2 = ((const float4*)p)[2];
        float4 r3 = ((const float4*)p)[3];
        float t[16] = {r0.x, r0.y, r0.z, r0.w, r1.x, r1.y, r1.z, r1.w,
                       r2.x, r2.y, r2.z, r2.w, r3.x, r3.y, r3.z, r3.w};
        float s = 0.f;
#pragma unroll
        for (int i = 0; i < 16; i++) s += t[i];
        float m = s * (1.f / 16.f);

        float vals[33];
#pragma unroll
        for (int i = 0; i < 16; i++) { vals[i] = m * t[i]; vals[16 + i] = t[i] * t[i]; }
        vals[32] = m * m;

        int wave = tid >> 6, lane = tid & 63;
#pragma unroll
        for (int i = 0; i < 33; i++) {
            float r = wave_sum(vals[i]);
            if (lane == 0) red[wave][i] = r;
        }
        __syncthreads();

        if (tid < 16) {
            int sI = tid;
            float dot = red[0][sI] + red[1][sI] + red[2][sI] + red[3][sI];
            float nb2 = red[0][16 + sI] + red[1][16 + sI] + red[2][16 + sI] + red[3][16 + sI];
            float na2 = red[0][32] + red[1][32] + red[2][32] + red[3][32];
            float w = dot / (fmaxf(sqrtf(na2), EPSF) * fmaxf(sqrtf(nb2), EPSF));
            float mx = w;
#pragma unroll
            for (int msk = 8; msk; msk >>= 1) mx = fmaxf(mx, __shfl_xor(mx, msk, 16));
            float e = expf(w - mx);
            float sm = e;
#pragma unroll
            for (int msk = 8; msk; msk >>= 1) sm += __shfl_xor(sm, msk, 16);
            float v = e / sm;
            wn[sI] = v;
            out3[b * 16 + sI] = v;
        }
        __syncthreads();

        float* o = out1 + ((size_t)(b * 257 + c)) * 16;
        ((float4*)o)[0] = r0; ((float4*)o)[1] = r1;
        ((float4*)o)[2] = r2; ((float4*)o)[3] = r3;
        if (tid < 16)
            out1[((size_t)(b * 257 + 256)) * 16 + tid] = wn[tid];
    }
}

// ---------------- K2: per-window cosine weight ----------------
// grid 64*73 blocks x 256 (4 waves; one window per wave, windows w=blk%73*4+wid).
// Lane owns 4 consecutive channels (float4 loads, coalesced 1KB/wave-instr).
// Reduction: na2 via wave_sum (no LDS); 32 rows [dot0..15, nb20..15] staged to
// per-wave LDS [32][65]; ALL 64 lanes sum half-rows (32 b32 reads, <=2-way
// banks = free), one shfl_xor(32) combine, one shfl to fetch nb2. No barrier:
// single-wave producer/consumer LDS.
__global__ void __launch_bounds__(256) k_cand_stats(
                             const float* __restrict__ candT,
                             float* __restrict__ wsW) {  // [b][4624] flat (i,j,p,q)
    __shared__ float red[4][32 * 65];
    int wid  = threadIdx.x >> 6;
    int lane = threadIdx.x & 63;
    int blk  = blockIdx.x;               // 0..4671
    int b    = blk / 73;
    int w    = (blk - b * 73) * 4 + wid; // window 0..291
    if (w > 288) return;
    int p = w / 17, q = w - p * 17;

    const float4* base = (const float4*)(candT + ((size_t)(b * 400 + p * 20 + q)) * 256) + lane;
    float4 wv[16];
#pragma unroll
    for (int di = 0; di < 4; di++)
#pragma unroll
        for (int dj = 0; dj < 4; dj++)
            wv[di * 4 + dj] = base[(size_t)(di * 20 + dj) * 64];

    float4 s4 = make_float4(0.f, 0.f, 0.f, 0.f);
#pragma unroll
    for (int t = 0; t < 16; t++) {
        s4.x += wv[t].x; s4.y += wv[t].y; s4.z += wv[t].z; s4.w += wv[t].w;
    }
    float4 m4 = make_float4(s4.x * (1.f/16.f), s4.y * (1.f/16.f),
                            s4.z * (1.f/16.f), s4.w * (1.f/16.f));

    float accDot[16], accNb2[16];
#pragma unroll
    for (int t = 0; t < 16; t++) {
        accDot[t] = m4.x * wv[t].x + m4.y * wv[t].y + m4.z * wv[t].z + m4.w * wv[t].w;
        accNb2[t] = wv[t].x * wv[t].x + wv[t].y * wv[t].y + wv[t].z * wv[t].z + wv[t].w * wv[t].w;
    }
    float accNa2 = m4.x * m4.x + m4.y * m4.y + m4.z * m4.z + m4.w * m4.w;

    float na2 = wave_sum(accNa2);

    float* R = red[wid];
#pragma unroll
    for (int i = 0; i < 16; i++) R[i * 65 + lane] = accDot[i];
#pragma unroll
    for (int i = 0; i < 16; i++) R[(16 + i) * 65 + lane] = accNb2[i];

    // all 64 lanes: lane = (row r 0..31, half h 0..1)
    int r = lane & 31, h = lane >> 5;
    const float* row = R + r * 65 + h * 32;
    float s = 0.f;
#pragma unroll
    for (int j = 0; j < 32; j++) s += row[j];
    s += __shfl_xor(s, 32, 64);          // full row sum in lanes r and r+32
    float nb2 = __shfl(s, (lane & 15) + 16, 64);  // row 16+i for lane i

    if (lane < 16) {
        float dot = s;                    // row lane = dot[lane]
        float w0 = dot / (fmaxf(sqrtf(na2), EPSF) * fmaxf(sqrtf(nb2), EPSF));
        // flat (i,j,p,q) order to match reshape(B,-1)
        wsW[(size_t)b * 4624 + lane * 289 + w] = w0;
    }
}

// ---------------- K3: per-batch softmax over 4624 ----------------
// grid 64, block 512. Contiguous reads of wsW.
__global__ void k_softmax(const float* __restrict__ wsW,
                          float* __restrict__ wsSm) {
    int b = blockIdx.x;
    int tid = threadIdx.x;
    __shared__ float wv[4624];
    __shared__ float red[8];
    __shared__ float bcast;
    int wave = tid >> 6, lane = tid & 63;

    float lmax = -1e30f;
    for (int f = tid; f < 4624; f += 512) {
        float w = wsW[(size_t)b * 4624 + f];
        wv[f] = w;
        lmax = fmaxf(lmax, w);
    }
#pragma unroll
    for (int m = 32; m; m >>= 1) lmax = fmaxf(lmax, __shfl_xor(lmax, m, 64));
    if (lane == 0) red[wave] = lmax;
    __syncthreads();
    if (tid == 0) {
        float M = red[0];
        for (int i = 1; i < 8; i++) M = fmaxf(M, red[i]);
        bcast = M;
    }
    __syncthreads();
    float M = bcast;

    float lsum = 0.f;
    for (int f = tid; f < 4624; f += 512) {
        float e = expf(wv[f] - M);
        wv[f] = e;
        lsum += e;
    }
    __syncthreads();
    lsum = wave_sum(lsum);
    if (lane == 0) red[wave] = lsum;
    __syncthreads();
    if (tid == 0) {
        float S = 0.f;
        for (int i = 0; i < 8; i++) S += red[i];
        bcast = S;
    }
    __syncthreads();
    float inv = 1.f / bcast;
    for (int f = tid; f < 4624; f += 512)
        wsSm[(size_t)b * 4624 + f] = wv[f] * inv;
}

// ---------------- K4: expansion writer ----------------
// grid (257, 64), block 256. ~305 MB of nontemporal float4 stores — the HBM
// floor (~50 us at the 6.35 TB/s the harness's own fill achieves).
__global__ void __launch_bounds__(256) k_writer(
                         const float* __restrict__ cand,
                         const float* __restrict__ wsSm,
                         float* __restrict__ out2,   // (64,257,4,4,17,17)
                         float* __restrict__ out4) { // (64,1,4,4,17,17)
    int ch = blockIdx.x;
    int b = blockIdx.y;
    int tid = threadIdx.x;
    __shared__ float lds[4624];

    if (ch < 256) {
        const float* src = cand + ((size_t)(b * 256 + ch)) * 400;
        if (tid < 256) lds[tid] = src[tid];
        if (tid < 144) lds[tid + 256] = src[tid + 256];
        __syncthreads();
        nvec4* ob = (nvec4*)(out2 + ((size_t)(b * 257 + ch)) * 4624);
#pragma unroll
        for (int it = 0; it < 5; it++) {
            int f4 = tid + it * 256;
            if (f4 < 1156) {
                int i  = f4 / 289;        // 0..3, constant within the float4
                int rr = f4 - i * 289;    // 0..288
                nvec4 vv;
#pragma unroll
                for (int e = 0; e < 4; e++) {
                    int r  = rr * 4 + e;      // 0..1155 in (j,p,q)
                    int j  = r / 289;
                    int r2 = r - j * 289;
                    int pp = r2 / 17;
                    int qq = r2 - pp * 17;
                    vv[e] = lds[(i + pp) * 20 + (j + qq)];
                }
                __builtin_nontemporal_store(vv, &ob[f4]);
            }
        }
    } else {
        const float* src = wsSm + (size_t)b * 4624;
        for (int f = tid; f < 4624; f += 256) lds[f] = src[f];
        __syncthreads();
        nvec4* ob = (nvec4*)(out2 + ((size_t)(b * 257 + 256)) * 4624);
        nvec4* o4 = (nvec4*)(out4 + (size_t)b * 4624);
#pragma unroll
        for (int it = 0; it < 5; it++) {
            int f4 = tid + it * 256;
            if (f4 < 1156) {
                int i  = f4 / 289;
                int rr = f4 - i * 289;
                nvec4 vv;
#pragma unroll
                for (int e = 0; e < 4; e++) {
                    int r  = rr * 4 + e;
                    int j  = r / 289;
                    int r2 = r - j * 289;
                    int pp = r2 / 17;
                    int qq = r2 - pp * 17;
                    // wc_norm[b,0,i,j,p,q] = sm_flat[(p*17+q)*16 + i*4 + j]
                    vv[e] = lds[(pp * 17 + qq) * 16 + i * 4 + j];
                }
                __builtin_nontemporal_store(vv, &ob[f4]);
                __builtin_nontemporal_store(vv, &o4[f4]);
            }
        }
    }
}

extern "C" void kernel_launch(void* const* d_in, const int* in_sizes, int n_in,
                              void* d_out, int out_size, void* d_ws, size_t ws_size,
                              hipStream_t stream) {
    const float* tpl  = (const float*)d_in[0];   // (64,256,4,4)
    const float* cand = (const float*)d_in[1];   // (64,256,20,20)
    float* out = (float*)d_out;
    // tuple flat-concat offsets
    float* out1 = out;                  // 263168
    float* out2 = out + 263168;         // 76067072
    float* out3 = out + 76330240;       // 1024
    float* out4 = out + 76331264;       // 295936

    float* ws = (float*)d_ws;
    float* wsW  = ws;                   // 64*4624 floats
    float* wsSm = ws + 295936;          // 64*4624 floats

    // candT (64,400,256) = 26.2 MB stashed at the head of out2's region.
    // Stream order: k_prep writes it, k_cand_stats reads it, k_writer later
    // overwrites all of out2.
    float* candT = out2;

    k_prep      <<<6720,          256, 0, stream>>>(cand, candT, tpl, out1, out3);
    k_cand_stats<<<64 * 73,       256, 0, stream>>>(candT, wsW);
    k_softmax   <<<64,            512, 0, stream>>>(wsW, wsSm);
    k_writer    <<<dim3(257, 64), 256, 0, stream>>>(cand, wsSm, out2, out4);
}